// Round 6
// baseline (1105.814 us; speedup 1.0000x reference)
//
#include <hip/hip_runtime.h>

#define BATCH   8
#define NPTS    8192
#define NPOINT  1024
#define NSAMPLE 32
#define CHANC   32
#define OUTC    35          // 3 xyz + 32 point channels
#define R2      0.0625f     // 0.25^2

#define NBLK    128                    // 8 fps + 120 workers, 1 block/CU (LDS)
#define NW      (NBLK - BATCH)         // worker blocks
#define NCTR    (BATCH * NPOINT)       // 8192 centers

typedef float v2f __attribute__((ext_vector_type(2)));
typedef unsigned long long u64;
typedef unsigned int u32;

// DPP helpers --------------------------------------------------------------
template <int CTRL>
__device__ __forceinline__ float dpp_max_step(float v) {
    int r = __builtin_amdgcn_update_dpp(__float_as_int(v), __float_as_int(v),
                                        CTRL, 0xf, 0xf, false);
    return fmaxf(v, __int_as_float(r));
}
#define DPP_ROW_SHR(n)  (0x110 | (n))
#define DPP_BCAST15     0x142
#define DPP_BCAST31     0x143

__device__ __forceinline__ u64 u64max(u64 a, u64 b) { return a > b ? a : b; }

// Barrier that drains ONLY LDS (lgkmcnt) — NOT vmcnt. The FPS loop's only
// outstanding VMEM ops are fire-and-forget tagged publishes (self-validating,
// written once, arbitrary delay safe) and new_xyz output stores (read only
// after kernel end; HW drains stores at s_endpgm). __syncthreads() would
// drain vmcnt(0) and eat the sc1 LLC-ack latency every iteration (R3/R4).
__device__ __forceinline__ void barrier_lds_only() {
    asm volatile("s_waitcnt lgkmcnt(0)\n\ts_barrier" ::: "memory");
}

// ---------------------------------------------------------------------------
// Fused persistent kernel — plain launch, 128 blocks (co-residency by
// capacity: 132 KB LDS forces 1 block/CU; 128 <= 256 CUs).
//  Blocks 0..7   : FPS, r0-verbatim compute path, lds-only in-loop barrier,
//                  3-lane parallel tagged publish (R5 structure, unchanged).
//  Blocks 8..127 : ballgroup workers, STATIC interleaved assignment (R6):
//                  block i owns center pairs (2i,2i+1), (2i+2NW,...). No job
//                  counter. Wave 0 alone polls the pair's 6 tagged words
//                  (6 lanes, one load per wake, s_sleep(64) backoff) and
//                  broadcasts via LDS; waves 1..7 park at __syncthreads —
//                  ~30x less spin traffic/power than R5's all-wave polling
//                  (theory: that contention cost fps +45 µs).
// ---------------------------------------------------------------------------
__global__ __launch_bounds__(512) void fused_kernel(
        const float* __restrict__ xyz,
        const float* __restrict__ points,
        float* __restrict__ new_xyz,
        float* __restrict__ out,
        u64* __restrict__ slots)
{
#pragma clang fp contract(off)
    __shared__ float4 pts[NPTS];                    // 128 KB, XOR-swizzled (fps)
    __shared__ u64 partial[2][8];                   // fps
    __shared__ int qidx[2][4][NSAMPLE];             // worker: 2 centers
    __shared__ int qcnt[2][4];
    __shared__ float ccsh[6];                       // worker: pair coords

    const int blk  = blockIdx.x;
    const int t    = threadIdx.x;
    const int lane = t & 63;

    if (blk < BATCH) {
        // ================= FPS role (R5-verbatim) =================
        const int b = blk;
        const int w = t >> 6;                       // wave id, 0..7
        const float* bx = xyz + (size_t)b * NPTS * 3;
        u64* bslot = slots + (size_t)b * NPOINT * 3;
        float* oxyz = new_xyz + (size_t)b * NPOINT * 3;

        // thread t owns points j = t*16 + i, i in [0,16): 48 consecutive floats
        v2f px[8], py[8], pz[8], dist[8];
        {
            float f[48];
            float4* fq = (float4*)f;
            const float4* s4 = (const float4*)bx + t * 12;
#pragma unroll
            for (int q = 0; q < 12; ++q) fq[q] = s4[q];
#pragma unroll
            for (int p = 0; p < 8; ++p) {
                px[p] = (v2f){f[6 * p + 0], f[6 * p + 3]};
                py[p] = (v2f){f[6 * p + 1], f[6 * p + 4]};
                pz[p] = (v2f){f[6 * p + 2], f[6 * p + 5]};
                dist[p] = (v2f){1e38f, 1e38f};
            }
#pragma unroll
            for (int i = 0; i < 16; ++i) {
                const int j  = t * 16 + i;
                const int js = j ^ ((j >> 4) & 7);  // bank swizzle
                pts[js] = make_float4(f[3 * i + 0], f[3 * i + 1], f[3 * i + 2], 0.0f);
            }
        }
        __syncthreads();

        // seed: xyz[b, 0]  (swizzle(0) == 0)
        float4 c0 = pts[0];
        float lx = c0.x, ly = c0.y, lz = c0.z;
        if (t < 3) {
            const float c = (t == 0) ? lx : (t == 1) ? ly : lz;
            const u64 tag = (u64)(u32)(b * NPOINT + 1);   // gw+1, s=0
            __hip_atomic_store(&bslot[t], (tag << 32) | (u64)__float_as_uint(c),
                               __ATOMIC_RELAXED, __HIP_MEMORY_SCOPE_AGENT);
            oxyz[t] = c;
        }

        for (int s = 1; s < NPOINT; ++s) {
            // --- packed update + serial inline argmax over 16 points ---
            const v2f lx2 = (v2f){lx, lx};
            const v2f ly2 = (v2f){ly, ly};
            const v2f lz2 = (v2f){lz, lz};
            float bestv = -1.0f;
            int   bi    = 0;
#pragma unroll
            for (int p = 0; p < 8; ++p) {
                const v2f dx = px[p] - lx2;
                const v2f dy = py[p] - ly2;
                const v2f dz = pz[p] - lz2;
                const v2f d2 = (dx * dx + dy * dy) + dz * dz;   // contract off -> exact
                const float d0 = fminf(dist[p].x, d2.x);
                const float d1 = fminf(dist[p].y, d2.y);
                dist[p] = (v2f){d0, d1};
                if (d0 > bestv) { bestv = d0; bi = 2 * p; }     // strict > keeps lowest i
                if (d1 > bestv) { bestv = d1; bi = 2 * p + 1; }
            }
            const int besti = (t << 4) + bi;

            // --- wave64 max via DPP (no LDS) ---
            float v = bestv;
            v = dpp_max_step<DPP_ROW_SHR(1)>(v);
            v = dpp_max_step<DPP_ROW_SHR(2)>(v);
            v = dpp_max_step<DPP_ROW_SHR(4)>(v);
            v = dpp_max_step<DPP_ROW_SHR(8)>(v);
            v = dpp_max_step<DPP_BCAST15>(v);
            v = dpp_max_step<DPP_BCAST31>(v);
            const float smax = __int_as_float(__builtin_amdgcn_readlane(__float_as_int(v), 63));

            // leader lane (lowest lane holding the max == lowest index) writes partial
            const u64 m   = __ballot(bestv == smax);
            const int par = s & 1;
            if (lane == (int)__builtin_ctzll(m)) {
                partial[par][w] = ((u64)__float_as_uint(smax) << 32)
                                  | (unsigned)(~besti);
            }
            barrier_lds_only();                     // drains LDS only, not vmcnt

            // --- all lanes scan the 8 partials: depth-3 u64 max tree ---
            const u64* P = partial[par];
            const u64 a0 = P[0], a1 = P[1], a2 = P[2], a3 = P[3];
            const u64 a4 = P[4], a5 = P[5], a6 = P[6], a7 = P[7];
            const u64 bp =
                u64max(u64max(u64max(a0, a1), u64max(a2, a3)),
                       u64max(u64max(a4, a5), u64max(a6, a7)));
            const int idx = (int)(~(unsigned)bp);
            const int js  = idx ^ ((idx >> 4) & 7);
            const float4 cw = pts[js];              // uniform -> broadcast b128
            lx = cw.x; ly = cw.y; lz = cw.z;
            // publish center (b,s): lanes 0..2 in parallel, fire-and-forget
            if (t < 3) {
                const float c = (t == 0) ? lx : (t == 1) ? ly : lz;
                const u64 tag = (u64)(u32)(b * NPOINT + s + 1);
                __hip_atomic_store(&bslot[3 * s + t],
                                   (tag << 32) | (u64)__float_as_uint(c),
                                   __ATOMIC_RELAXED, __HIP_MEMORY_SCOPE_AGENT);
                oxyz[3 * s + t] = c;
            }
        }
    } else {
        // ================= worker role (static assignment) =================
        const int wb = blk - BATCH;                 // 0..NW-1
        for (int g0 = wb * 2; g0 < NCTR; g0 += NW * 2) {
            // --- wave 0 polls the pair's 6 tagged words; others park ---
            if ((t >> 6) == 0) {
                const int  gwl  = g0 + (lane >= 3 ? 1 : 0);
                u64* sl  = (lane < 6) ? slots + (size_t)gwl * 3 + (lane % 3)
                                      : slots;          // dummy for lanes 6..63
                const u32 tagl = (lane < 6) ? (u32)(gwl + 1) : 0u;
                u64 rv;
                for (;;) {
                    rv = __hip_atomic_load(sl, __ATOMIC_RELAXED,
                                           __HIP_MEMORY_SCOPE_AGENT);
                    const bool ready = (lane >= 6) | ((u32)(rv >> 32) == tagl);
                    if (__ballot(ready) == ~0ull) break;
                    __builtin_amdgcn_s_sleep(64);
                }
                if (lane < 6) ccsh[lane] = __uint_as_float((u32)rv);
            }
            __syncthreads();                        // coords ready; qidx reusable

            const int half = t >> 8;                // 0: center A, 1: center B
            const int gw   = g0 + half;             // center id
            const int bb   = gw >> 10;
            const int r    = (t >> 6) & 3;          // quarter within center group
            const float cx = ccsh[half * 3 + 0];
            const float cy = ccsh[half * 3 + 1];
            const float cz = ccsh[half * 3 + 2];

            // --- scan this wave's quarter: 2048 pts, 8 superrounds of 256 ---
            const float* bxr = xyz + (size_t)bb * NPTS * 3;
            int k = 0;
            const int qbase = r << 11;
            for (int base = qbase; base < qbase + 2048; base += 256) {
                float qx[4], qy[4], qz[4];
#pragma unroll
                for (int u = 0; u < 4; ++u) {
                    const int j = base + u * 64 + lane;
                    qx[u] = bxr[3 * j + 0];
                    qy[u] = bxr[3 * j + 1];
                    qz[u] = bxr[3 * j + 2];
                }
                bool in[4];
#pragma unroll
                for (int u = 0; u < 4; ++u) {
                    const float dx = qx[u] - cx;
                    const float dy = qy[u] - cy;
                    const float dz = qz[u] - cz;
                    const float d2 = (dx * dx + dy * dy) + dz * dz;   // contract off
                    in[u] = d2 < R2;
                }
#pragma unroll
                for (int u = 0; u < 4; ++u) {
                    const u64 mu = __ballot(in[u]);
                    const int pre = __popcll(mu & ((1ull << lane) - 1ull));
                    if (in[u] && (k + pre) < NSAMPLE) qidx[half][r][k + pre] = base + u * 64 + lane;
                    k += __popcll(mu);
                }
                if (k >= NSAMPLE) break;            // one exit check per superround
            }
            if (k > NSAMPLE) k = NSAMPLE;
            if (lane == 0) qcnt[half][r] = k;
            __syncthreads();

            // --- prefix-merge: first NSAMPLE of the concatenated quarters ---
            const int c0n = qcnt[half][0], c1n = qcnt[half][1];
            const int c2n = qcnt[half][2], c3n = qcnt[half][3];
            const int o1 = c0n, o2 = c0n + c1n, o3 = o2 + c2n;
            const int total = o3 + c3n;
            const int kk = total < NSAMPLE ? total : NSAMPLE;
            const int rq = (c0n > 0) ? 0 : (c1n > 0) ? 1 : (c2n > 0) ? 2 : 3;
            const int firstIdx = qidx[half][rq][0];

            // --- gather: 32x35 output elems across 256 threads, coalesced ---
            float*       o    = out + (size_t)gw * NSAMPLE * OUTC;
            const float* prow = points + (size_t)bb * NPTS * CHANC;
            const int t256 = t & 255;
            for (int e = t256; e < NSAMPLE * OUTC; e += 256) {
                const int sI = e / OUTC;
                const int c  = e - sI * OUTC;
                int j;
                if (sI < kk) {
                    const int rr  = (int)(sI >= o1) + (int)(sI >= o2) + (int)(sI >= o3);
                    const int off = (rr == 0) ? 0 : (rr == 1) ? o1 : (rr == 2) ? o2 : o3;
                    j = qidx[half][rr][sI - off];
                } else {
                    j = firstIdx;
                }
                float v;
                if (c < 3) {
                    const float pv = bxr[3 * j + c];
                    const float cc = (c == 0) ? cx : (c == 1) ? cy : cz;
                    v = pv - cc;
                } else {
                    v = prow[j * CHANC + (c - 3)];
                }
                o[e] = v;   // consecutive lanes -> consecutive addresses (coalesced)
            }
            // next pair: top __syncthreads separates qidx/ccsh reuse
        }
    }
}

// ---------------------------------------------------------------------------
extern "C" void kernel_launch(void* const* d_in, const int* in_sizes, int n_in,
                              void* d_out, int out_size, void* d_ws, size_t ws_size,
                              hipStream_t stream) {
    const float* xyz    = (const float*)d_in[0];   // (8, 8192, 3)  fp32
    const float* points = (const float*)d_in[1];   // (8, 8192, 32) fp32
    float* new_xyz    = (float*)d_out;                         // (8,1024,3)
    float* new_points = new_xyz + (size_t)BATCH * NPOINT * 3;  // (8,1024,32,35)

    u64* slots = (u64*)d_ws;                       // 8192 x 3 tagged words

    // kill stale tags from previous graph replay (192 KB)
    hipMemsetAsync(slots, 0, (size_t)NCTR * 3 * sizeof(u64), stream);

    // plain launch: co-residency by capacity (128 blocks, 1/CU LDS-forced)
    fused_kernel<<<NBLK, 512, 0, stream>>>(xyz, points, new_xyz, new_points,
                                           slots);
}

// Round 7
// 969.212 us; speedup vs baseline: 1.1409x; 1.1409x over previous
//
#include <hip/hip_runtime.h>

#define BATCH   8
#define NPTS    8192
#define NPOINT  1024
#define NSAMPLE 32
#define CHANC   32
#define OUTC    35          // 3 xyz + 32 point channels
#define R2      0.0625f     // 0.25^2

#define NBLK    64                     // 8 fps + 56 workers, 1 block/CU (LDS)
#define NW      (NBLK - BATCH)         // worker blocks
#define NCTR    (BATCH * NPOINT)       // 8192 centers
#define NJOB    (NCTR / 2)             // 4096 jobs (2 centers each)

typedef float v2f __attribute__((ext_vector_type(2)));
typedef unsigned long long u64;
typedef unsigned int u32;

// DPP helpers --------------------------------------------------------------
template <int CTRL>
__device__ __forceinline__ float dpp_max_step(float v) {
    int r = __builtin_amdgcn_update_dpp(__float_as_int(v), __float_as_int(v),
                                        CTRL, 0xf, 0xf, false);
    return fmaxf(v, __int_as_float(r));
}
#define DPP_ROW_SHR(n)  (0x110 | (n))
#define DPP_BCAST15     0x142
#define DPP_BCAST31     0x143

__device__ __forceinline__ u64 u64max(u64 a, u64 b) { return a > b ? a : b; }

// Barrier that drains ONLY LDS (lgkmcnt) — NOT vmcnt. The FPS loop's only
// outstanding VMEM ops are fire-and-forget tagged publishes (self-validating,
// written once, arbitrary delay safe) and new_xyz output stores (read only
// after kernel end; HW drains stores at s_endpgm). __syncthreads() would
// drain vmcnt(0) and eat the sc1 LLC-ack latency every iteration (R3/R4).
__device__ __forceinline__ void barrier_lds_only() {
    asm volatile("s_waitcnt lgkmcnt(0)\n\ts_barrier" ::: "memory");
}

// ---------------------------------------------------------------------------
// Fused persistent kernel — plain launch, 64 blocks (co-residency by
// capacity: 132 KB LDS forces 1 block/CU; 64 <= 256 CUs).
//  Blocks 0..7  : FPS, r0-verbatim compute path, lds-only in-loop barrier,
//                 3-lane parallel tagged publish (R5 structure, unchanged).
//  Blocks 8..63 : ballgroup workers, static assignment in READINESS ORDER
//                 (R7): job J covers centers (b=J&7, s=2(J>>3)) and
//                 (b, 2(J>>3)+1) — s-major/batch-minor, matching fps
//                 production order across the 8 parallel fps blocks. Worker
//                 wb takes J = wb, wb+NW, ...: readiness spacing NW/8 x
//                 1.74 µs >> ~4 µs job cost, so workers stay readiness-
//                 gated and the post-fps tail is ~one job (R6's gw-major
//                 order serialized batch-0 and left a ~115 µs tail).
//                 Wave 0 alone polls the pair's 6 tagged words (6 lanes,
//                 s_sleep(64) backoff), broadcasts via LDS; waves 1..7 park
//                 at __syncthreads.
// ---------------------------------------------------------------------------
__global__ __launch_bounds__(512) void fused_kernel(
        const float* __restrict__ xyz,
        const float* __restrict__ points,
        float* __restrict__ new_xyz,
        float* __restrict__ out,
        u64* __restrict__ slots)
{
#pragma clang fp contract(off)
    __shared__ float4 pts[NPTS];                    // 128 KB, XOR-swizzled (fps)
    __shared__ u64 partial[2][8];                   // fps
    __shared__ int qidx[2][4][NSAMPLE];             // worker: 2 centers
    __shared__ int qcnt[2][4];
    __shared__ float ccsh[6];                       // worker: pair coords

    const int blk  = blockIdx.x;
    const int t    = threadIdx.x;
    const int lane = t & 63;

    if (blk < BATCH) {
        // ================= FPS role (R5-verbatim) =================
        const int b = blk;
        const int w = t >> 6;                       // wave id, 0..7
        const float* bx = xyz + (size_t)b * NPTS * 3;
        u64* bslot = slots + (size_t)b * NPOINT * 3;
        float* oxyz = new_xyz + (size_t)b * NPOINT * 3;

        // thread t owns points j = t*16 + i, i in [0,16): 48 consecutive floats
        v2f px[8], py[8], pz[8], dist[8];
        {
            float f[48];
            float4* fq = (float4*)f;
            const float4* s4 = (const float4*)bx + t * 12;
#pragma unroll
            for (int q = 0; q < 12; ++q) fq[q] = s4[q];
#pragma unroll
            for (int p = 0; p < 8; ++p) {
                px[p] = (v2f){f[6 * p + 0], f[6 * p + 3]};
                py[p] = (v2f){f[6 * p + 1], f[6 * p + 4]};
                pz[p] = (v2f){f[6 * p + 2], f[6 * p + 5]};
                dist[p] = (v2f){1e38f, 1e38f};
            }
#pragma unroll
            for (int i = 0; i < 16; ++i) {
                const int j  = t * 16 + i;
                const int js = j ^ ((j >> 4) & 7);  // bank swizzle
                pts[js] = make_float4(f[3 * i + 0], f[3 * i + 1], f[3 * i + 2], 0.0f);
            }
        }
        __syncthreads();

        // seed: xyz[b, 0]  (swizzle(0) == 0)
        float4 c0 = pts[0];
        float lx = c0.x, ly = c0.y, lz = c0.z;
        if (t < 3) {
            const float c = (t == 0) ? lx : (t == 1) ? ly : lz;
            const u64 tag = (u64)(u32)(b * NPOINT + 1);   // gw+1, s=0
            __hip_atomic_store(&bslot[t], (tag << 32) | (u64)__float_as_uint(c),
                               __ATOMIC_RELAXED, __HIP_MEMORY_SCOPE_AGENT);
            oxyz[t] = c;
        }

        for (int s = 1; s < NPOINT; ++s) {
            // --- packed update + serial inline argmax over 16 points ---
            const v2f lx2 = (v2f){lx, lx};
            const v2f ly2 = (v2f){ly, ly};
            const v2f lz2 = (v2f){lz, lz};
            float bestv = -1.0f;
            int   bi    = 0;
#pragma unroll
            for (int p = 0; p < 8; ++p) {
                const v2f dx = px[p] - lx2;
                const v2f dy = py[p] - ly2;
                const v2f dz = pz[p] - lz2;
                const v2f d2 = (dx * dx + dy * dy) + dz * dz;   // contract off -> exact
                const float d0 = fminf(dist[p].x, d2.x);
                const float d1 = fminf(dist[p].y, d2.y);
                dist[p] = (v2f){d0, d1};
                if (d0 > bestv) { bestv = d0; bi = 2 * p; }     // strict > keeps lowest i
                if (d1 > bestv) { bestv = d1; bi = 2 * p + 1; }
            }
            const int besti = (t << 4) + bi;

            // --- wave64 max via DPP (no LDS) ---
            float v = bestv;
            v = dpp_max_step<DPP_ROW_SHR(1)>(v);
            v = dpp_max_step<DPP_ROW_SHR(2)>(v);
            v = dpp_max_step<DPP_ROW_SHR(4)>(v);
            v = dpp_max_step<DPP_ROW_SHR(8)>(v);
            v = dpp_max_step<DPP_BCAST15>(v);
            v = dpp_max_step<DPP_BCAST31>(v);
            const float smax = __int_as_float(__builtin_amdgcn_readlane(__float_as_int(v), 63));

            // leader lane (lowest lane holding the max == lowest index) writes partial
            const u64 m   = __ballot(bestv == smax);
            const int par = s & 1;
            if (lane == (int)__builtin_ctzll(m)) {
                partial[par][w] = ((u64)__float_as_uint(smax) << 32)
                                  | (unsigned)(~besti);
            }
            barrier_lds_only();                     // drains LDS only, not vmcnt

            // --- all lanes scan the 8 partials: depth-3 u64 max tree ---
            const u64* P = partial[par];
            const u64 a0 = P[0], a1 = P[1], a2 = P[2], a3 = P[3];
            const u64 a4 = P[4], a5 = P[5], a6 = P[6], a7 = P[7];
            const u64 bp =
                u64max(u64max(u64max(a0, a1), u64max(a2, a3)),
                       u64max(u64max(a4, a5), u64max(a6, a7)));
            const int idx = (int)(~(unsigned)bp);
            const int js  = idx ^ ((idx >> 4) & 7);
            const float4 cw = pts[js];              // uniform -> broadcast b128
            lx = cw.x; ly = cw.y; lz = cw.z;
            // publish center (b,s): lanes 0..2 in parallel, fire-and-forget
            if (t < 3) {
                const float c = (t == 0) ? lx : (t == 1) ? ly : lz;
                const u64 tag = (u64)(u32)(b * NPOINT + s + 1);
                __hip_atomic_store(&bslot[3 * s + t],
                                   (tag << 32) | (u64)__float_as_uint(c),
                                   __ATOMIC_RELAXED, __HIP_MEMORY_SCOPE_AGENT);
                oxyz[3 * s + t] = c;
            }
        }
    } else {
        // ============ worker role (static, readiness-ordered) ============
        const int wb = blk - BATCH;                 // 0..NW-1
        for (int J = wb; J < NJOB; J += NW) {
            const int bb = J & 7;                   // batch
            const int uu = J >> 3;                  // pair index within batch
            const int g0 = bb * NPOINT + 2 * uu;    // centers g0, g0+1

            // --- wave 0 polls the pair's 6 tagged words; others park ---
            if ((t >> 6) == 0) {
                const int  gwl = g0 + (lane >= 3 ? 1 : 0);
                u64* sl  = (lane < 6) ? slots + (size_t)gwl * 3 + (lane % 3)
                                      : slots;          // dummy for lanes 6..63
                const u32 tagl = (lane < 6) ? (u32)(gwl + 1) : 0u;
                u64 rv;
                for (;;) {
                    rv = __hip_atomic_load(sl, __ATOMIC_RELAXED,
                                           __HIP_MEMORY_SCOPE_AGENT);
                    const bool ready = (lane >= 6) | ((u32)(rv >> 32) == tagl);
                    if (__ballot(ready) == ~0ull) break;
                    __builtin_amdgcn_s_sleep(64);
                }
                if (lane < 6) ccsh[lane] = __uint_as_float((u32)rv);
            }
            __syncthreads();                        // coords ready; qidx reusable

            const int half = t >> 8;                // 0: center A, 1: center B
            const int gw   = g0 + half;             // center id
            const int r    = (t >> 6) & 3;          // quarter within center group
            const float cx = ccsh[half * 3 + 0];
            const float cy = ccsh[half * 3 + 1];
            const float cz = ccsh[half * 3 + 2];

            // --- scan this wave's quarter: 2048 pts, 8 superrounds of 256 ---
            const float* bxr = xyz + (size_t)bb * NPTS * 3;
            int k = 0;
            const int qbase = r << 11;
            for (int base = qbase; base < qbase + 2048; base += 256) {
                float qx[4], qy[4], qz[4];
#pragma unroll
                for (int u = 0; u < 4; ++u) {
                    const int j = base + u * 64 + lane;
                    qx[u] = bxr[3 * j + 0];
                    qy[u] = bxr[3 * j + 1];
                    qz[u] = bxr[3 * j + 2];
                }
                bool in[4];
#pragma unroll
                for (int u = 0; u < 4; ++u) {
                    const float dx = qx[u] - cx;
                    const float dy = qy[u] - cy;
                    const float dz = qz[u] - cz;
                    const float d2 = (dx * dx + dy * dy) + dz * dz;   // contract off
                    in[u] = d2 < R2;
                }
#pragma unroll
                for (int u = 0; u < 4; ++u) {
                    const u64 mu = __ballot(in[u]);
                    const int pre = __popcll(mu & ((1ull << lane) - 1ull));
                    if (in[u] && (k + pre) < NSAMPLE) qidx[half][r][k + pre] = base + u * 64 + lane;
                    k += __popcll(mu);
                }
                if (k >= NSAMPLE) break;            // one exit check per superround
            }
            if (k > NSAMPLE) k = NSAMPLE;
            if (lane == 0) qcnt[half][r] = k;
            __syncthreads();

            // --- prefix-merge: first NSAMPLE of the concatenated quarters ---
            const int c0n = qcnt[half][0], c1n = qcnt[half][1];
            const int c2n = qcnt[half][2], c3n = qcnt[half][3];
            const int o1 = c0n, o2 = c0n + c1n, o3 = o2 + c2n;
            const int total = o3 + c3n;
            const int kk = total < NSAMPLE ? total : NSAMPLE;
            const int rq = (c0n > 0) ? 0 : (c1n > 0) ? 1 : (c2n > 0) ? 2 : 3;
            const int firstIdx = qidx[half][rq][0];

            // --- gather: 32x35 output elems across 256 threads, coalesced ---
            float*       o    = out + (size_t)gw * NSAMPLE * OUTC;
            const float* prow = points + (size_t)bb * NPTS * CHANC;
            const int t256 = t & 255;
            for (int e = t256; e < NSAMPLE * OUTC; e += 256) {
                const int sI = e / OUTC;
                const int c  = e - sI * OUTC;
                int j;
                if (sI < kk) {
                    const int rr  = (int)(sI >= o1) + (int)(sI >= o2) + (int)(sI >= o3);
                    const int off = (rr == 0) ? 0 : (rr == 1) ? o1 : (rr == 2) ? o2 : o3;
                    j = qidx[half][rr][sI - off];
                } else {
                    j = firstIdx;
                }
                float v;
                if (c < 3) {
                    const float pv = bxr[3 * j + c];
                    const float cc = (c == 0) ? cx : (c == 1) ? cy : cz;
                    v = pv - cc;
                } else {
                    v = prow[j * CHANC + (c - 3)];
                }
                o[e] = v;   // consecutive lanes -> consecutive addresses (coalesced)
            }
            // next pair: top __syncthreads separates qidx/ccsh reuse
        }
    }
}

// ---------------------------------------------------------------------------
extern "C" void kernel_launch(void* const* d_in, const int* in_sizes, int n_in,
                              void* d_out, int out_size, void* d_ws, size_t ws_size,
                              hipStream_t stream) {
    const float* xyz    = (const float*)d_in[0];   // (8, 8192, 3)  fp32
    const float* points = (const float*)d_in[1];   // (8, 8192, 32) fp32
    float* new_xyz    = (float*)d_out;                         // (8,1024,3)
    float* new_points = new_xyz + (size_t)BATCH * NPOINT * 3;  // (8,1024,32,35)

    u64* slots = (u64*)d_ws;                       // 8192 x 3 tagged words

    // kill stale tags from previous graph replay (192 KB)
    hipMemsetAsync(slots, 0, (size_t)NCTR * 3 * sizeof(u64), stream);

    // plain launch: co-residency by capacity (64 blocks, 1/CU LDS-forced)
    fused_kernel<<<NBLK, 512, 0, stream>>>(xyz, points, new_xyz, new_points,
                                           slots);
}